// Round 7
// baseline (1204.877 us; speedup 1.0000x reference)
//
#include <hip/hip_runtime.h>
#include <hip/hip_bf16.h>
#include <cstdint>

#define B_ 2
#define N_ 2048
#define H_ 16
#define HID_ 2048
#define QR_ 1536
#define KVR_ 512
#define DN_ 128
#define DR_ 64
#define DV_ 128
#define QHD_ 192

typedef __attribute__((ext_vector_type(8))) short short8;
typedef __attribute__((ext_vector_type(4))) float f32x4;

union bfu { __hip_bfloat16 b; short s; };

// split v into bf16 hi (RNE) + bf16 lo of the remainder (error ~2^-18 rel)
static __device__ __forceinline__ void bf_split(float v, short& hi, short& lo) {
  bfu uh, ul;
  uh.b = __float2bfloat16(v);
  float hf = __bfloat162float(uh.b);
  ul.b = __float2bfloat16(v - hf);
  hi = uh.s; lo = ul.s;
}

// async global->LDS, 16B per lane; LDS dest = wave-uniform base + lane*16
static __device__ __forceinline__ void gload16(const void* g, void* l) {
  __builtin_amdgcn_global_load_lds(
      (const __attribute__((address_space(1))) uint32_t*)(g),
      (__attribute__((address_space(3))) uint32_t*)(l), 16, 0, 0);
}

// counted-vmcnt wait + workgroup barrier (T4 pattern; sched_barrier per rule #18)
#define VM_BARRIER(N)                                   \
  do {                                                  \
    asm volatile("s_waitcnt vmcnt(" #N ")" ::: "memory"); \
    __builtin_amdgcn_sched_barrier(0);                  \
    __builtin_amdgcn_s_barrier();                       \
    __builtin_amdgcn_sched_barrier(0);                  \
  } while (0)

#define LGKM_BARRIER()                                  \
  do {                                                  \
    asm volatile("s_waitcnt lgkmcnt(0)" ::: "memory");  \
    __builtin_amdgcn_sched_barrier(0);                  \
    __builtin_amdgcn_s_barrier();                       \
    __builtin_amdgcn_sched_barrier(0);                  \
  } while (0)

// ---------------------------------------------------------------------------
// Tile-image format: per (rowblock, ks) tile of 128 rows x 64 k bf16 = 16KB.
// Row r at r*128B; 16B slot s (k = s*8..s*8+7) at byte ((16*s) ^ ((r&7)<<4)).
// A3 k-segments: [Ahi | Alo | Ahi];  B3: [Bhi | Bhi | Blo]  (Keff = 3K).
// ---------------------------------------------------------------------------

__global__ __launch_bounds__(256) void conv_a_kernel(
    const float* __restrict__ A, uint8_t* __restrict__ img, int K, int nks, int total) {
  int gid = blockIdx.x * 256 + threadIdx.x;
  if (gid >= total) return;
  int perRow = K >> 3;
  int row = gid / perRow, kc = (gid - row * perRow) << 3;
  const float* src = A + (size_t)row * K + kc;
  short8 hi, lo;
#pragma unroll
  for (int j = 0; j < 8; ++j) { short a, b; bf_split(src[j], a, b); hi[j] = a; lo[j] = b; }
  int mb = row >> 7, r = row & 127, sw = (r & 7) << 4;
  uint8_t* base = img + ((size_t)mb * nks << 14) + r * 128;
  auto put = [&](int p, short8 v) {
    int ks = p >> 6, s = (p >> 3) & 7;
    *(short8*)(base + ((size_t)ks << 14) + ((16 * s) ^ sw)) = v;
  };
  put(kc, hi); put(K + kc, lo); put(2 * K + kc, hi);
}

__global__ __launch_bounds__(256) void conv_b_kernel(
    const float* __restrict__ Bw, uint8_t* __restrict__ img, int K, int N,
    int Npad, int nbase, int nks, int total) {
  int gid = blockIdx.x * 256 + threadIdx.x;
  if (gid >= total) return;
  int perN = K >> 3;
  int n = gid / perN, kc = (gid - n * perN) << 3;
  short8 hi = {0,0,0,0,0,0,0,0}, lo = {0,0,0,0,0,0,0,0};
  if (n < N) {
#pragma unroll
    for (int j = 0; j < 8; ++j) {
      short a, b; bf_split(Bw[(size_t)(kc + j) * N + n], a, b); hi[j] = a; lo[j] = b;
    }
  }
  int nn = nbase * 128 + n;
  int nb = nn >> 7, r = nn & 127, sw = (r & 7) << 4;
  uint8_t* base = img + ((size_t)nb * nks << 14) + r * 128;
  auto put = [&](int p, short8 v) {
    int ks = p >> 6, s = (p >> 3) & 7;
    *(short8*)(base + ((size_t)ks << 14) + ((16 * s) ^ sw)) = v;
  };
  put(kc, hi); put(K + kc, hi); put(2 * K + kc, lo);
}

// rmsnorm fused into A3 image emission.  One block per row.
__global__ __launch_bounds__(256) void rmsnorm_img_kernel(
    const float* __restrict__ in, const float* __restrict__ w,
    uint8_t* __restrict__ img, int len, int istride, int nks) {
  __shared__ float red[4];
  const int row = blockIdx.x;
  const float* x = in + (size_t)row * istride;
  float ss = 0.f;
  for (int i = threadIdx.x; i < len; i += 256) { float v = x[i]; ss += v * v; }
#pragma unroll
  for (int o = 32; o > 0; o >>= 1) ss += __shfl_down(ss, o, 64);
  if ((threadIdx.x & 63) == 0) red[threadIdx.x >> 6] = ss;
  __syncthreads();
  if (threadIdx.x == 0)
    red[0] = rsqrtf((red[0] + red[1] + red[2] + red[3]) / (float)len + 1e-6f);
  __syncthreads();
  const float inv = red[0];
  int mb = row >> 7, r = row & 127, sw = (r & 7) << 4;
  uint8_t* base = img + ((size_t)mb * nks << 14) + r * 128;
  auto put = [&](int p, short8 v) {
    int ks = p >> 6, s = (p >> 3) & 7;
    *(short8*)(base + ((size_t)ks << 14) + ((16 * s) ^ sw)) = v;
  };
  for (int kc = threadIdx.x * 8; kc < len; kc += 2048) {
    short8 hi, lo;
#pragma unroll
    for (int j = 0; j < 8; ++j) {
      short a, b; bf_split(w[kc + j] * (x[kc + j] * inv), a, b); hi[j] = a; lo[j] = b;
    }
    put(kc, hi); put(len + kc, lo); put(2 * len + kc, hi);
  }
}

// ---------------------------------------------------------------------------
// bf16 MFMA GEMM: 128x128 tile, BK=64, 4 waves (2x2), 4x4 16x16x32 frags.
// C fp32 row-major (ldc = N).
// ---------------------------------------------------------------------------
__global__ __launch_bounds__(256) void gemm_bf16_kernel(
    const uint8_t* __restrict__ Aimg, const uint8_t* __restrict__ Bimg,
    float* __restrict__ C, int N, int nks) {
  __shared__ __align__(16) uint8_t As[16384];
  __shared__ __align__(16) uint8_t Bs[16384];
  const int tid = threadIdx.x;
  const int lane = tid & 63;
  const int wave = tid >> 6;
  const int wm = wave >> 1, wn = wave & 1;
  const int lr = lane & 15, g = lane >> 4;
  const int mb = blockIdx.y, nb = blockIdx.x;
  const uint8_t* ga = Aimg + ((size_t)mb * nks << 14);
  const uint8_t* gb = Bimg + ((size_t)nb * nks << 14);

  f32x4 acc[4][4];
#pragma unroll
  for (int i = 0; i < 4; ++i)
#pragma unroll
    for (int j = 0; j < 4; ++j) acc[i][j] = (f32x4){0.f, 0.f, 0.f, 0.f};

  for (int ks = 0; ks < nks; ++ks) {
    __syncthreads();
#pragma unroll
    for (int i = 0; i < 4; ++i)
      gload16(ga + ((size_t)ks << 14) + (wave * 4 + i) * 1024 + lane * 16,
              As + (wave * 4 + i) * 1024);
#pragma unroll
    for (int i = 0; i < 4; ++i)
      gload16(gb + ((size_t)ks << 14) + (wave * 4 + i) * 1024 + lane * 16,
              Bs + (wave * 4 + i) * 1024);
    __syncthreads();
#pragma unroll
    for (int c = 0; c < 2; ++c) {
      short8 af[4], bf[4];
#pragma unroll
      for (int i = 0; i < 4; ++i) {
        int ar = wm * 64 + i * 16 + lr;
        af[i] = *(const short8*)(As + ar * 128 + ((16 * (c * 4 + g)) ^ ((ar & 7) << 4)));
        int br = wn * 64 + i * 16 + lr;
        bf[i] = *(const short8*)(Bs + br * 128 + ((16 * (c * 4 + g)) ^ ((br & 7) << 4)));
      }
#pragma unroll
      for (int i = 0; i < 4; ++i)
#pragma unroll
        for (int j = 0; j < 4; ++j)
          acc[i][j] = __builtin_amdgcn_mfma_f32_16x16x32_bf16(af[i], bf[j], acc[i][j], 0, 0, 0);
    }
  }
#pragma unroll
  for (int i = 0; i < 4; ++i)
#pragma unroll
    for (int q = 0; q < 4; ++q) {
      float* rp = C + (size_t)(mb * 128 + wm * 64 + i * 16 + g * 4 + q) * N +
                  nb * 128 + wn * 64 + lr;
#pragma unroll
      for (int j = 0; j < 4; ++j) rp[j * 16] = acc[i][j][q];
    }
}

// ---------------------------------------------------------------------------
// conv_kn: kv_up fp32 -> K_nope tile image (32 rows x 512B per (bh,kt) tile).
// ---------------------------------------------------------------------------
__global__ __launch_bounds__(256) void conv_kn_kernel(
    const float* __restrict__ kv_up, uint8_t* __restrict__ Kn) {
  const int kt = blockIdx.x, bh = blockIdx.y;
  const int b = bh >> 4, h = bh & 15;
  uint8_t* tile = Kn + (((size_t)bh * 64 + kt) << 14);
  for (int f = threadIdx.x; f < 512; f += 256) {
    int r = f >> 4, s = f & 15;
    int tok = b * N_ + kt * 32 + r;
    const float* src = kv_up + (size_t)tok * 4096 + h * 256 + s * 8;
    short8 hi, lo;
#pragma unroll
    for (int j = 0; j < 8; ++j) { short a, bq; bf_split(src[j], a, bq); hi[j] = a; lo[j] = bq; }
    int sw = (r & 7) << 4;
    *(short8*)(tile + r * 512 + ((16 * s) ^ sw)) = hi;
    *(short8*)(tile + r * 512 + ((16 * (s + 16)) ^ sw)) = lo;
  }
}

// ---------------------------------------------------------------------------
// conv_v: kv_up fp32 -> V-transposed tile image (128 d-rows x 128B per tile).
// ---------------------------------------------------------------------------
__global__ __launch_bounds__(256) void conv_v_kernel(
    const float* __restrict__ kv_up, uint8_t* __restrict__ Vimg) {
  const int kt = blockIdx.x, bh = blockIdx.y;
  const int b = bh >> 4, h = bh & 15;
  uint8_t* tile = Vimg + (((size_t)bh * 64 + kt) << 14);
  for (int f = threadIdx.x; f < 512; f += 256) {
    int d = f >> 2, gg = f & 3;
    int tok0 = b * N_ + kt * 32 + gg * 8;
    short8 hi, lo;
#pragma unroll
    for (int j = 0; j < 8; ++j) {
      short a, bq;
      bf_split(kv_up[(size_t)(tok0 + j) * 4096 + h * 256 + 128 + d], a, bq);
      hi[j] = a; lo[j] = bq;
    }
    int sw = (d & 7) << 4;
    *(short8*)(tile + d * 128 + ((16 * gg) ^ sw)) = hi;
    *(short8*)(tile + d * 128 + ((16 * (4 + gg)) ^ sw)) = lo;
  }
}

// ---------------------------------------------------------------------------
// RoPE (permute_pairs + rotate_half fused)
// ---------------------------------------------------------------------------
__device__ __forceinline__ void rope_apply(const float* __restrict__ src,
                                           float* __restrict__ dst, float pos) {
  float xv[64];
#pragma unroll
  for (int i = 0; i < 64; ++i) xv[i] = src[i];
#pragma unroll
  for (int i = 0; i < 32; ++i) {
    float freq = __expf(-0.2878231366f * (float)i);
    float s, c;
    sincosf(pos * freq, &s, &c);
    dst[i]      = xv[2 * i] * c - xv[2 * i + 1] * s;
    dst[i + 32] = xv[2 * i + 1] * c + xv[2 * i] * s;
  }
}

__global__ __launch_bounds__(256) void rope_q_kernel(float* __restrict__ q,
                                                     const int* __restrict__ pos_ids) {
  int idx = blockIdx.x * 256 + threadIdx.x;  // t*16 + h
  if (idx >= B_ * N_ * H_) return;
  int t = idx >> 4, h = idx & 15;
  float* p = q + (size_t)t * (H_ * QHD_) + h * QHD_ + DN_;
  rope_apply(p, p, (float)pos_ids[t]);
}

// rope_k -> kpe tile image: per (b,kt) 32 rows x 256B (hi slots 0-7, lo 8-15)
__global__ __launch_bounds__(256) void rope_k_kernel(const float* __restrict__ Cmat,
                                                     const int* __restrict__ pos_ids,
                                                     uint8_t* __restrict__ Kp) {
  int t = blockIdx.x * 256 + threadIdx.x;
  if (t >= B_ * N_) return;
  float rv[64];
  rope_apply(Cmat + (size_t)t * 2176 + 2048, rv, (float)pos_ids[t]);
  int b = t >> 11, tt = t & 2047, kt = tt >> 5, r = tt & 31;
  uint8_t* tp = Kp + (((size_t)b * 64 + kt) << 13) + r * 256;
  int sw = (r & 7) << 4;
#pragma unroll
  for (int s = 0; s < 8; ++s) {
    short8 hi, lo;
#pragma unroll
    for (int j = 0; j < 8; ++j) { short a, bq; bf_split(rv[s * 8 + j], a, bq); hi[j] = a; lo[j] = bq; }
    *(short8*)(tp + ((16 * s) ^ sw)) = hi;
    *(short8*)(tp + ((16 * (s + 8)) ^ sw)) = lo;
  }
}

// ---------------------------------------------------------------------------
// MFMA flash attention (bf16 hi/lo).  4 waves x 32 q-rows; KB=32.
// NEW: counted-vmcnt software pipeline (T3/T4-lite): Kn double-buffered;
// Kn(t+1) issued before QK^T(t); Kp(t+1) after QK^T barrier; V(t+1) after
// PV barrier.  vmcnt(4) waits exploit in-order VMEM retirement.  s_setprio
// around MFMA clusters (T5).  LDS 72KB -> 2 blocks/CU.
// ---------------------------------------------------------------------------
__global__ __launch_bounds__(256, 2) void attn_mfma_kernel(
    const float* __restrict__ q_up,   // (B*N, H*192) roped fp32
    const uint8_t* __restrict__ Kn, const uint8_t* __restrict__ Kp,
    const uint8_t* __restrict__ Vv,
    float* __restrict__ aout) {       // (B*N, H*128)
  __shared__ __align__(16) uint8_t Ksn[2][32 * 512];  // 32K (double-buffered)
  __shared__ __align__(16) uint8_t Ksp[32 * 256];     // 8K
  __shared__ __align__(16) uint8_t Vs[128 * 128];     // 16K
  __shared__ __align__(16) uint8_t Ps[4 * 4096];      // 16K   => 72K total

  const int tid = threadIdx.x;
  const int lane = tid & 63;
  const int wave = tid >> 6;
  const int g = lane >> 4;
  const int lr = lane & 15;
  const int bh = blockIdx.y;
  const int b = bh >> 4, h = bh & 15;
  const int q0 = blockIdx.x << 7;   // 128 q-rows per block

  short8 qhi[2][6], qlo[2][6];
  {
    const float scale = 0.07216878364870323f;  // 1/sqrt(192)
#pragma unroll
    for (int tl = 0; tl < 2; ++tl) {
      const int tok = b * N_ + q0 + wave * 32 + tl * 16 + lr;
      const float* qp = q_up + (size_t)tok * (H_ * QHD_) + h * QHD_;
#pragma unroll
      for (int c = 0; c < 6; ++c) {
        const float* src = qp + c * 32 + g * 8;
#pragma unroll
        for (int j = 0; j < 8; ++j) {
          short a, bq; bf_split(src[j] * scale, a, bq);
          qhi[tl][c][j] = a; qlo[tl][c][j] = bq;
        }
      }
    }
  }

  f32x4 acc_o[2][8];
#pragma unroll
  for (int tl = 0; tl < 2; ++tl)
#pragma unroll
    for (int i = 0; i < 8; ++i) acc_o[tl][i] = (f32x4){0.f, 0.f, 0.f, 0.f};
  float m_r[2][4], l_r[2][4];
#pragma unroll
  for (int tl = 0; tl < 2; ++tl)
#pragma unroll
    for (int j = 0; j < 4; ++j) { m_r[tl][j] = -1e30f; l_r[tl][j] = 0.f; }

  const size_t knbase = ((size_t)bh * 64) << 14;
  const size_t kpbase = ((size_t)b * 64) << 13;
  const size_t vbase  = ((size_t)bh * 64) << 14;

  // prologue: stage Kn(0)/Kp(0)/V(0); wait Kn+Kp (6 newest = V stay in flight)
  {
    const uint8_t* gkn = Kn + knbase;
    const uint8_t* gkp = Kp + kpbase;
    const uint8_t* gv  = Vv + vbase;
#pragma unroll
    for (int i = 0; i < 4; ++i)
      gload16(gkn + (wave * 4 + i) * 1024 + lane * 16, Ksn[0] + (wave * 4 + i) * 1024);
#pragma unroll
    for (int i = 0; i < 2; ++i)
      gload16(gkp + (wave * 2 + i) * 1024 + lane * 16, Ksp + (wave * 2 + i) * 1024);
#pragma unroll
    for (int i = 0; i < 4; ++i)
      gload16(gv + (wave * 4 + i) * 1024 + lane * 16, Vs + (wave * 4 + i) * 1024);
  }
  VM_BARRIER(4);   // Kn(0), Kp(0) landed; V(0) (4 newest) still in flight

  int cbuf = 0;
  for (int kt = 0; kt < N_ / 32; ++kt) {
    const int ktn = (kt + 1 < N_ / 32) ? kt + 1 : kt;  // clamp keeps vmcnt uniform

    // ---- issue Kn(t+1) -> Ksn[cbuf^1] (hidden under QK^T/softmax) ----
    {
      const uint8_t* gkn = Kn + knbase + ((size_t)ktn << 14);
#pragma unroll
      for (int i = 0; i < 4; ++i)
        gload16(gkn + (wave * 4 + i) * 1024 + lane * 16,
                Ksn[cbuf ^ 1] + (wave * 4 + i) * 1024);
    }

    // ---- QK^T from Ksn[cbuf] / Ksp: per K-fragment read -> 6 MFMAs ----
    f32x4 accs[2][2];
    __builtin_amdgcn_s_setprio(1);
#pragma unroll
    for (int t = 0; t < 2; ++t) {
      f32x4 aA = {0.f, 0.f, 0.f, 0.f};
      f32x4 aB = {0.f, 0.f, 0.f, 0.f};
      const int krow = t * 16 + lr;
      const int sw = (krow & 7) << 4;
      const uint8_t* kb = Ksn[cbuf] + krow * 512;
#pragma unroll
      for (int c = 0; c < 4; ++c) {
        short8 kh = *(const short8*)(kb + ((16 * (c * 4 + g)) ^ sw));
        short8 kl = *(const short8*)(kb + ((16 * (c * 4 + g + 16)) ^ sw));
        aA = __builtin_amdgcn_mfma_f32_16x16x32_bf16(qhi[0][c], kh, aA, 0, 0, 0);
        aA = __builtin_amdgcn_mfma_f32_16x16x32_bf16(qhi[0][c], kl, aA, 0, 0, 0);
        aA = __builtin_amdgcn_mfma_f32_16x16x32_bf16(qlo[0][c], kh, aA, 0, 0, 0);
        aB = __builtin_amdgcn_mfma_f32_16x16x32_bf16(qhi[1][c], kh, aB, 0, 0, 0);
        aB = __builtin_amdgcn_mfma_f32_16x16x32_bf16(qhi[1][c], kl, aB, 0, 0, 0);
        aB = __builtin_amdgcn_mfma_f32_16x16x32_bf16(qlo[1][c], kh, aB, 0, 0, 0);
      }
      const uint8_t* pb = Ksp + krow * 256;
#pragma unroll
      for (int c2 = 0; c2 < 2; ++c2) {
        short8 kh = *(const short8*)(pb + ((16 * (c2 * 4 + g)) ^ sw));
        short8 kl = *(const short8*)(pb + ((16 * (c2 * 4 + g + 8)) ^ sw));
        aA = __builtin_amdgcn_mfma_f32_16x16x32_bf16(qhi[0][4 + c2], kh, aA, 0, 0, 0);
        aA = __builtin_amdgcn_mfma_f32_16x16x32_bf16(qhi[0][4 + c2], kl, aA, 0, 0, 0);
        aA = __builtin_amdgcn_mfma_f32_16x16x32_bf16(qlo[0][4 + c2], kh, aA, 0, 0, 0);
        aB = __builtin_amdgcn_mfma_f32_16x16x32_bf16(qhi[1][4 + c2], kh, aB, 0, 0, 0);
        aB = __builtin_amdgcn_mfma_f32_16x16x32_bf16(qhi[1][4 + c2], kl, aB, 0, 0, 0);
        aB = __builtin_amdgcn_mfma_f32_16x16x32_bf16(qlo[1][4 + c2], kh, aB, 0, 0, 0);
      }
      accs[0][t] = aA; accs[1][t] = aB;
    }
    __builtin_amdgcn_s_setprio(0);

    // ---- online softmax + rescale (V(t) still landing underneath) ----
    float fac[2][4], p0[2][4], p1[2][4];
#pragma unroll
    for (int tl = 0; tl < 2; ++tl)
#pragma unroll
      for (int j = 0; j < 4; ++j) {
        float rm = fmaxf(accs[tl][0][j], accs[tl][1][j]);
        rm = fmaxf(rm, __shfl_xor(rm, 1, 64));
        rm = fmaxf(rm, __shfl_xor(rm, 2, 64));
        rm = fmaxf(rm, __shfl_xor(rm, 4, 64));
        rm = fmaxf(rm, __shfl_xor(rm, 8, 64));
        float mn = fmaxf(m_r[tl][j], rm);
        fac[tl][j] = __expf(m_r[tl][j] - mn);
        m_r[tl][j] = mn;
        p0[tl][j] = __expf(accs[tl][0][j] - mn);
        p1[tl][j] = __expf(accs[tl][1][j] - mn);
        float rs = p0[tl][j] + p1[tl][j];
        rs += __shfl_xor(rs, 1, 64);
        rs += __shfl_xor(rs, 2, 64);
        rs += __shfl_xor(rs, 4, 64);
        rs += __shfl_xor(rs, 8, 64);
        l_r[tl][j] = l_r[tl][j] * fac[tl][j] + rs;
      }
#pragma unroll
    for (int tl = 0; tl < 2; ++tl)
#pragma unroll
      for (int dt = 0; dt < 8; ++dt)
#pragma unroll
        for (int j = 0; j < 4; ++j) acc_o[tl][dt][j] *= fac[tl][j];

    // ---- b1: V(t) visible (4 oldest retire; Kn(t+1) stays); Ksp now free ----
    VM_BARRIER(4);

    // ---- issue Kp(t+1) -> Ksp (hidden under P-write + PV) ----
    {
      const uint8_t* gkp = Kp + kpbase + ((size_t)ktn << 13);
#pragma unroll
      for (int i = 0; i < 2; ++i)
        gload16(gkp + (wave * 2 + i) * 1024 + lane * 16, Ksp + (wave * 2 + i) * 1024);
    }

    // ---- P (hi/lo) -> per-wave swizzled LDS ----
#pragma unroll
    for (int tl = 0; tl < 2; ++tl) {
      uint8_t* pw = Ps + wave * 4096 + tl * 2048;
#pragma unroll
      for (int j = 0; j < 4; ++j) {
        int r = g * 4 + j;
        int rsw = (r & 7) << 4;
        uint8_t* rowp = pw + r * 128;
#pragma unroll
        for (int t = 0; t < 2; ++t) {
          float p = t ? p1[tl][j] : p0[tl][j];
          int k = t * 16 + lr;
          short a, bq; bf_split(p, a, bq);
          *(short*)(rowp + ((((k >> 3) + 0) * 16) ^ rsw) + (k & 7) * 2) = a;
          *(short*)(rowp + ((((k >> 3) + 4) * 16) ^ rsw) + (k & 7) * 2) = bq;
        }
      }
    }

    // ---- PV: per V-fragment read -> 6 MFMAs ----
    {
      const uint8_t* prA = Ps + wave * 4096 + lr * 128;
      const uint8_t* prB = prA + 2048;
      const int psw = (lr & 7) << 4;
      short8 phA = *(const short8*)(prA + ((16 * g) ^ psw));
      short8 plA = *(const short8*)(prA + ((16 * (4 + g)) ^ psw));
      short8 phB = *(const short8*)(prB + ((16 * g) ^ psw));
      short8 plB = *(const short8*)(prB + ((16 * (4 + g)) ^ psw));
      __builtin_amdgcn_s_setprio(1);
#pragma unroll
      for (int dt = 0; dt < 8; ++dt) {
        int dcol = dt * 16 + lr;
        const uint8_t* vb = Vs + dcol * 128;
        int vsw = (dcol & 7) << 4;
        short8 vh = *(const short8*)(vb + ((16 * g) ^ vsw));
        short8 vl = *(const short8*)(vb + ((16 * (4 + g)) ^ vsw));
        acc_o[0][dt] = __builtin_amdgcn_mfma_f32_16x16x32_bf16(phA, vh, acc_o[0][dt], 0, 0, 0);
        acc_o[0][dt] = __builtin_amdgcn_mfma_f32_16x16x32_bf16(phA, vl, acc_o[0][dt], 0, 0, 0);
        acc_o[0][dt] = __builtin_amdgcn_mfma_f32_16x16x32_bf16(plA, vh, acc_o[0][dt], 0, 0, 0);
        acc_o[1][dt] = __builtin_amdgcn_mfma_f32_16x16x32_bf16(phB, vh, acc_o[1][dt], 0, 0, 0);
        acc_o[1][dt] = __builtin_amdgcn_mfma_f32_16x16x32_bf16(phB, vl, acc_o[1][dt], 0, 0, 0);
        acc_o[1][dt] = __builtin_amdgcn_mfma_f32_16x16x32_bf16(plB, vh, acc_o[1][dt], 0, 0, 0);
      }
      __builtin_amdgcn_s_setprio(0);
    }

    // ---- b2: all waves done reading Vs -> safe to restage ----
    LGKM_BARRIER();

    // ---- issue V(t+1) -> Vs ----
    {
      const uint8_t* gv = Vv + vbase + ((size_t)ktn << 14);
#pragma unroll
      for (int i = 0; i < 4; ++i)
        gload16(gv + (wave * 4 + i) * 1024 + lane * 16, Vs + (wave * 4 + i) * 1024);
    }

    // ---- b3: Kn(t+1)+Kp(t+1) landed (V(t+1), 4 newest, stays in flight) ----
    VM_BARRIER(4);
    cbuf ^= 1;
  }

  // ---- epilogue ----
#pragma unroll
  for (int tl = 0; tl < 2; ++tl) {
    float inv[4];
#pragma unroll
    for (int j = 0; j < 4; ++j) inv[j] = 1.f / l_r[tl][j];
    const int tokb = b * N_ + q0 + wave * 32 + tl * 16 + g * 4;
#pragma unroll
    for (int j = 0; j < 4; ++j) {
      float* orow = aout + (size_t)(tokb + j) * (H_ * DV_) + h * DV_;
#pragma unroll
      for (int dt = 0; dt < 8; ++dt)
        orow[dt * 16 + lr] = acc_o[tl][dt][j] * inv[j];
    }
  }
}

// ---------------------------------------------------------------------------
extern "C" void kernel_launch(void* const* d_in, const int* in_sizes, int n_in,
                              void* d_out, int out_size, void* d_ws, size_t ws_size,
                              hipStream_t stream) {
  (void)in_sizes; (void)n_in; (void)out_size; (void)ws_size;
  const float* x         = (const float*)d_in[0];
  const float* Wq_down   = (const float*)d_in[1];
  const float* q_norm_w  = (const float*)d_in[2];
  const float* Wq_up     = (const float*)d_in[3];
  const float* Wkv_down  = (const float*)d_in[4];
  const float* kv_norm_w = (const float*)d_in[5];
  const float* Wkv_up    = (const float*)d_in[6];
  const float* Wo        = (const float*)d_in[7];
  const int* pos_ids     = (const int*)d_in[9];
  float* out = (float*)d_out;

  // ws byte layout (peak ~167MB < 194MB proven):
  uint8_t* W = (uint8_t*)d_ws;
  uint8_t* Xi    = W;                          // 48MB x-image (also q-norm img 36MB)
  uint8_t* Bslot = W + 50331648;               // 28.3MB weight images
  float*   qtkv  = (float*)(W + 79691776);     // 4096 x 2176 fp32 (34MB)
  float*   q_up  = (float*)(W + 115343360);    // 4096 x 3072 fp32 (48MB)
  uint8_t* Kpimg = W + 165675008;              // 1MB
  uint8_t* KvAimg= W + 67108864;               // 12MB (kv rmsnorm image)
  uint8_t* WkvBimg=W + 79691776;               // 12MB (reuses dead qtkv)
  float*   kv_up = (float*)(W + 0);            // 64MB fp32 (reuses dead x/q images)
  uint8_t* Knimg = W + 67108864;               // 32MB
  float*   a_out = (float*)(W + 0);            // 32MB (reuses dead kv_up)
  uint8_t* A2img = W + 33554432;               // 48MB
  uint8_t* Woimg = W + 100663296;              // 24MB
  uint8_t* Vimg  = (uint8_t*)d_out;            // 32MB (dead before final GEMM)

  dim3 blk(256);
  // down-proj: x-img, [Wq_down | Wkv_down]-img, one GEMM (N = 1536+640pad)
  conv_a_kernel<<<4096, blk, 0, stream>>>(x, Xi, 2048, 96, 4096 * 256);
  conv_b_kernel<<<1536, blk, 0, stream>>>(Wq_down, Bslot, 2048, 1536, 1536, 0, 96, 1536 * 256);
  conv_b_kernel<<<640, blk, 0, stream>>>(Wkv_down, Bslot, 2048, 576, 640, 12, 96, 640 * 256);
  gemm_bf16_kernel<<<dim3(17, 32), blk, 0, stream>>>(Xi, Bslot, qtkv, 2176, 96);
  // q path
  rmsnorm_img_kernel<<<4096, blk, 0, stream>>>(qtkv, q_norm_w, Xi, 1536, 2176, 72);
  conv_b_kernel<<<2304, blk, 0, stream>>>(Wq_up, Bslot, 1536, 3072, 3072, 0, 72, 2304 * 256);
  gemm_bf16_kernel<<<dim3(24, 32), blk, 0, stream>>>(Xi, Bslot, q_up, 3072, 72);
  rope_q_kernel<<<256, blk, 0, stream>>>(q_up, pos_ids);
  // kv path (consume qtkv, then reuse its space)
  rope_k_kernel<<<16, blk, 0, stream>>>(qtkv, pos_ids, Kpimg);
  rmsnorm_img_kernel<<<4096, blk, 0, stream>>>(qtkv + 1536, kv_norm_w, KvAimg, 512, 2176, 24);
  conv_b_kernel<<<1024, blk, 0, stream>>>(Wkv_up, WkvBimg, 512, 4096, 4096, 0, 24, 1024 * 256);
  gemm_bf16_kernel<<<dim3(32, 32), blk, 0, stream>>>(KvAimg, WkvBimg, kv_up, 4096, 24);
  conv_kn_kernel<<<dim3(64, 32), blk, 0, stream>>>(kv_up, Knimg);
  conv_v_kernel<<<dim3(64, 32), blk, 0, stream>>>(kv_up, Vimg);
  // attention (128 q-rows per block, pipelined)
  attn_mfma_kernel<<<dim3(16, 32), blk, 0, stream>>>(q_up, Knimg, Kpimg, Vimg, a_out);
  // output projection
  conv_a_kernel<<<4096, blk, 0, stream>>>(a_out, A2img, 2048, 96, 4096 * 256);
  conv_b_kernel<<<2048, blk, 0, stream>>>(Wo, Woimg, 2048, 2048, 2048, 0, 96, 2048 * 256);
  gemm_bf16_kernel<<<dim3(16, 32), blk, 0, stream>>>(A2img, Woimg, out, 2048, 96);
}

// Round 9
// 1127.483 us; speedup vs baseline: 1.0686x; 1.0686x over previous
//
#include <hip/hip_runtime.h>
#include <hip/hip_bf16.h>
#include <cstdint>

#define B_ 2
#define N_ 2048
#define H_ 16
#define HID_ 2048
#define QR_ 1536
#define KVR_ 512
#define DN_ 128
#define DR_ 64
#define DV_ 128
#define QHD_ 192

typedef __attribute__((ext_vector_type(8))) short short8;
typedef __attribute__((ext_vector_type(4))) float f32x4;

union bfu { __hip_bfloat16 b; short s; };

// split v into bf16 hi (RNE) + bf16 lo of the remainder (error ~2^-18 rel)
static __device__ __forceinline__ void bf_split(float v, short& hi, short& lo) {
  bfu uh, ul;
  uh.b = __float2bfloat16(v);
  float hf = __bfloat162float(uh.b);
  ul.b = __float2bfloat16(v - hf);
  hi = uh.s; lo = ul.s;
}

// async global->LDS, 16B per lane; LDS dest = wave-uniform base + lane*16
static __device__ __forceinline__ void gload16(const void* g, void* l) {
  __builtin_amdgcn_global_load_lds(
      (const __attribute__((address_space(1))) uint32_t*)(g),
      (__attribute__((address_space(3))) uint32_t*)(l), 16, 0, 0);
}

// ---------------------------------------------------------------------------
// Tile-image format: per (rowblock, ks) tile of 128 rows x 64 k bf16 = 16KB.
// Row r at r*128B; 16B slot s (k = s*8..s*8+7) at byte ((16*s) ^ ((r&7)<<4)).
// A3 k-segments: [Ahi | Alo | Ahi];  B3: [Bhi | Bhi | Blo]  (Keff = 3K).
// ---------------------------------------------------------------------------

__global__ __launch_bounds__(256) void conv_a_kernel(
    const float* __restrict__ A, uint8_t* __restrict__ img, int K, int nks, int total) {
  int gid = blockIdx.x * 256 + threadIdx.x;
  if (gid >= total) return;
  int perRow = K >> 3;
  int row = gid / perRow, kc = (gid - row * perRow) << 3;
  const float* src = A + (size_t)row * K + kc;
  short8 hi, lo;
#pragma unroll
  for (int j = 0; j < 8; ++j) { short a, b; bf_split(src[j], a, b); hi[j] = a; lo[j] = b; }
  int mb = row >> 7, r = row & 127, sw = (r & 7) << 4;
  uint8_t* base = img + ((size_t)mb * nks << 14) + r * 128;
  auto put = [&](int p, short8 v) {
    int ks = p >> 6, s = (p >> 3) & 7;
    *(short8*)(base + ((size_t)ks << 14) + ((16 * s) ^ sw)) = v;
  };
  put(kc, hi); put(K + kc, lo); put(2 * K + kc, hi);
}

// conv_b: LDS-transposed, coalesced.  Block handles a 64k x 64n fp32
// tile: coalesced row-major loads into padded LDS, then each thread emits
// 16B image chunks (8 k-values of one column) from LDS.  [64][65] pad ->
// stride 65 % 32 banks => <=2-way aliasing (free).
__global__ __launch_bounds__(256) void conv_b_kernel(
    const float* __restrict__ Bw, uint8_t* __restrict__ img, int K, int N,
    int nbase, int nks) {
  __shared__ float tile[64][65];
  const int t = threadIdx.x;
  const int n0 = blockIdx.x << 6;   // col block within padded N
  const int k0 = blockIdx.y << 6;   // k block
#pragma unroll
  for (int i = 0; i < 16; ++i) {
    int row = i * 4 + (t >> 6);
    int col = t & 63;
    int n = n0 + col;
    tile[row][col] = (n < N) ? Bw[(size_t)(k0 + row) * N + n] : 0.f;
  }
  __syncthreads();
#pragma unroll
  for (int half = 0; half < 2; ++half) {
    int u = t + half * 256;            // 512 units = 64 cols x 8 k-chunks
    int n_local = u >> 3, kcl = (u & 7) << 3;
    int nn = nbase * 128 + n0 + n_local;
    int nb = nn >> 7, r = nn & 127, sw = (r & 7) << 4;
    uint8_t* base = img + ((size_t)nb * nks << 14) + r * 128;
    short8 hi, lo;
#pragma unroll
    for (int j = 0; j < 8; ++j) {
      short a, b2; bf_split(tile[kcl + j][n_local], a, b2); hi[j] = a; lo[j] = b2;
    }
    auto put = [&](int p, short8 v) {
      int ks = p >> 6, s = (p >> 3) & 7;
      *(short8*)(base + ((size_t)ks << 14) + ((16 * s) ^ sw)) = v;
    };
    int kc = k0 + kcl;
    put(kc, hi); put(K + kc, hi); put(2 * K + kc, lo);
  }
}

// rmsnorm fused into A3 image emission.  One block per row.
__global__ __launch_bounds__(256) void rmsnorm_img_kernel(
    const float* __restrict__ in, const float* __restrict__ w,
    uint8_t* __restrict__ img, int len, int istride, int nks) {
  __shared__ float red[4];
  const int row = blockIdx.x;
  const float* x = in + (size_t)row * istride;
  float ss = 0.f;
  for (int i = threadIdx.x; i < len; i += 256) { float v = x[i]; ss += v * v; }
#pragma unroll
  for (int o = 32; o > 0; o >>= 1) ss += __shfl_down(ss, o, 64);
  if ((threadIdx.x & 63) == 0) red[threadIdx.x >> 6] = ss;
  __syncthreads();
  if (threadIdx.x == 0)
    red[0] = rsqrtf((red[0] + red[1] + red[2] + red[3]) / (float)len + 1e-6f);
  __syncthreads();
  const float inv = red[0];
  int mb = row >> 7, r = row & 127, sw = (r & 7) << 4;
  uint8_t* base = img + ((size_t)mb * nks << 14) + r * 128;
  auto put = [&](int p, short8 v) {
    int ks = p >> 6, s = (p >> 3) & 7;
    *(short8*)(base + ((size_t)ks << 14) + ((16 * s) ^ sw)) = v;
  };
  for (int kc = threadIdx.x * 8; kc < len; kc += 2048) {
    short8 hi, lo;
#pragma unroll
    for (int j = 0; j < 8; ++j) {
      short a, b; bf_split(w[kc + j] * (x[kc + j] * inv), a, b); hi[j] = a; lo[j] = b;
    }
    put(kc, hi); put(len + kc, lo); put(2 * len + kc, hi);
  }
}

// ---------------------------------------------------------------------------
// bf16 MFMA GEMM: 128x128 tile, BK=64, 4 waves (2x2), 4x4 16x16x32 frags.
// C fp32 row-major (ldc = N).
// ---------------------------------------------------------------------------
__global__ __launch_bounds__(256) void gemm_bf16_kernel(
    const uint8_t* __restrict__ Aimg, const uint8_t* __restrict__ Bimg,
    float* __restrict__ C, int N, int nks) {
  __shared__ __align__(16) uint8_t As[16384];
  __shared__ __align__(16) uint8_t Bs[16384];
  const int tid = threadIdx.x;
  const int lane = tid & 63;
  const int wave = tid >> 6;
  const int wm = wave >> 1, wn = wave & 1;
  const int lr = lane & 15, g = lane >> 4;
  const int mb = blockIdx.y, nb = blockIdx.x;
  const uint8_t* ga = Aimg + ((size_t)mb * nks << 14);
  const uint8_t* gb = Bimg + ((size_t)nb * nks << 14);

  f32x4 acc[4][4];
#pragma unroll
  for (int i = 0; i < 4; ++i)
#pragma unroll
    for (int j = 0; j < 4; ++j) acc[i][j] = (f32x4){0.f, 0.f, 0.f, 0.f};

  for (int ks = 0; ks < nks; ++ks) {
    __syncthreads();
#pragma unroll
    for (int i = 0; i < 4; ++i)
      gload16(ga + ((size_t)ks << 14) + (wave * 4 + i) * 1024 + lane * 16,
              As + (wave * 4 + i) * 1024);
#pragma unroll
    for (int i = 0; i < 4; ++i)
      gload16(gb + ((size_t)ks << 14) + (wave * 4 + i) * 1024 + lane * 16,
              Bs + (wave * 4 + i) * 1024);
    __syncthreads();
#pragma unroll
    for (int c = 0; c < 2; ++c) {
      short8 af[4], bf[4];
#pragma unroll
      for (int i = 0; i < 4; ++i) {
        int ar = wm * 64 + i * 16 + lr;
        af[i] = *(const short8*)(As + ar * 128 + ((16 * (c * 4 + g)) ^ ((ar & 7) << 4)));
        int br = wn * 64 + i * 16 + lr;
        bf[i] = *(const short8*)(Bs + br * 128 + ((16 * (c * 4 + g)) ^ ((br & 7) << 4)));
      }
#pragma unroll
      for (int i = 0; i < 4; ++i)
#pragma unroll
        for (int j = 0; j < 4; ++j)
          acc[i][j] = __builtin_amdgcn_mfma_f32_16x16x32_bf16(af[i], bf[j], acc[i][j], 0, 0, 0);
    }
  }
#pragma unroll
  for (int i = 0; i < 4; ++i)
#pragma unroll
    for (int q = 0; q < 4; ++q) {
      float* rp = C + (size_t)(mb * 128 + wm * 64 + i * 16 + g * 4 + q) * N +
                  nb * 128 + wn * 64 + lr;
#pragma unroll
      for (int j = 0; j < 4; ++j) rp[j * 16] = acc[i][j][q];
    }
}

// ---------------------------------------------------------------------------
// conv_kn: kv_up fp32 -> K_nope tile image (32 rows x 512B per (bh,kt) tile).
// ---------------------------------------------------------------------------
__global__ __launch_bounds__(256) void conv_kn_kernel(
    const float* __restrict__ kv_up, uint8_t* __restrict__ Kn) {
  const int kt = blockIdx.x, bh = blockIdx.y;
  const int b = bh >> 4, h = bh & 15;
  uint8_t* tile = Kn + (((size_t)bh * 64 + kt) << 14);
  for (int f = threadIdx.x; f < 512; f += 256) {
    int r = f >> 4, s = f & 15;
    int tok = b * N_ + kt * 32 + r;
    const float* src = kv_up + (size_t)tok * 4096 + h * 256 + s * 8;
    short8 hi, lo;
#pragma unroll
    for (int j = 0; j < 8; ++j) { short a, bq; bf_split(src[j], a, bq); hi[j] = a; lo[j] = bq; }
    int sw = (r & 7) << 4;
    *(short8*)(tile + r * 512 + ((16 * s) ^ sw)) = hi;
    *(short8*)(tile + r * 512 + ((16 * (s + 16)) ^ sw)) = lo;
  }
}

// ---------------------------------------------------------------------------
// conv_v: kv_up fp32 -> V-transposed tile image (128 d-rows x 128B per tile).
// ---------------------------------------------------------------------------
__global__ __launch_bounds__(256) void conv_v_kernel(
    const float* __restrict__ kv_up, uint8_t* __restrict__ Vimg) {
  const int kt = blockIdx.x, bh = blockIdx.y;
  const int b = bh >> 4, h = bh & 15;
  uint8_t* tile = Vimg + (((size_t)bh * 64 + kt) << 14);
  for (int f = threadIdx.x; f < 512; f += 256) {
    int d = f >> 2, gg = f & 3;
    int tok0 = b * N_ + kt * 32 + gg * 8;
    short8 hi, lo;
#pragma unroll
    for (int j = 0; j < 8; ++j) {
      short a, bq;
      bf_split(kv_up[(size_t)(tok0 + j) * 4096 + h * 256 + 128 + d], a, bq);
      hi[j] = a; lo[j] = bq;
    }
    int sw = (d & 7) << 4;
    *(short8*)(tile + d * 128 + ((16 * gg) ^ sw)) = hi;
    *(short8*)(tile + d * 128 + ((16 * (4 + gg)) ^ sw)) = lo;
  }
}

// ---------------------------------------------------------------------------
// RoPE (permute_pairs + rotate_half fused)
// ---------------------------------------------------------------------------
__device__ __forceinline__ void rope_apply(const float* __restrict__ src,
                                           float* __restrict__ dst, float pos) {
  float xv[64];
#pragma unroll
  for (int i = 0; i < 64; ++i) xv[i] = src[i];
#pragma unroll
  for (int i = 0; i < 32; ++i) {
    float freq = __expf(-0.2878231366f * (float)i);
    float s, c;
    sincosf(pos * freq, &s, &c);
    dst[i]      = xv[2 * i] * c - xv[2 * i + 1] * s;
    dst[i + 32] = xv[2 * i + 1] * c + xv[2 * i] * s;
  }
}

__global__ __launch_bounds__(256) void rope_q_kernel(float* __restrict__ q,
                                                     const int* __restrict__ pos_ids) {
  int idx = blockIdx.x * 256 + threadIdx.x;  // t*16 + h
  if (idx >= B_ * N_ * H_) return;
  int t = idx >> 4, h = idx & 15;
  float* p = q + (size_t)t * (H_ * QHD_) + h * QHD_ + DN_;
  rope_apply(p, p, (float)pos_ids[t]);
}

// rope_k -> kpe tile image: per (b,kt) 32 rows x 256B (hi slots 0-7, lo 8-15)
__global__ __launch_bounds__(256) void rope_k_kernel(const float* __restrict__ Cmat,
                                                     const int* __restrict__ pos_ids,
                                                     uint8_t* __restrict__ Kp) {
  int t = blockIdx.x * 256 + threadIdx.x;
  if (t >= B_ * N_) return;
  float rv[64];
  rope_apply(Cmat + (size_t)t * 2176 + 2048, rv, (float)pos_ids[t]);
  int b = t >> 11, tt = t & 2047, kt = tt >> 5, r = tt & 31;
  uint8_t* tp = Kp + (((size_t)b * 64 + kt) << 13) + r * 256;
  int sw = (r & 7) << 4;
#pragma unroll
  for (int s = 0; s < 8; ++s) {
    short8 hi, lo;
#pragma unroll
    for (int j = 0; j < 8; ++j) { short a, bq; bf_split(rv[s * 8 + j], a, bq); hi[j] = a; lo[j] = bq; }
    *(short8*)(tp + ((16 * s) ^ sw)) = hi;
    *(short8*)(tp + ((16 * (s + 8)) ^ sw)) = lo;
  }
}

// ---------------------------------------------------------------------------
// MFMA flash attention (bf16 hi/lo).  4 waves x 32 q-rows (2 fragment tiles)
// = 128 q-rows/block; KB=32.  Round-6 measured version (384us, MfmaUtil
// 29.5%): plain 2-barrier staging; the counted-vmcnt pipeline (round 7)
// regressed -9% -- extra barrier + sched fences cost more than prefetch
// gained (cross-block overlap already hides staging).
// ---------------------------------------------------------------------------
__global__ __launch_bounds__(256, 2) void attn_mfma_kernel(
    const float* __restrict__ q_up,   // (B*N, H*192) roped fp32
    const uint8_t* __restrict__ Kn, const uint8_t* __restrict__ Kp,
    const uint8_t* __restrict__ Vv,
    float* __restrict__ aout) {       // (B*N, H*128)
  __shared__ __align__(16) uint8_t Ksn[32 * 512];
  __shared__ __align__(16) uint8_t Ksp[32 * 256];
  __shared__ __align__(16) uint8_t Vs[128 * 128];
  __shared__ __align__(16) uint8_t Ps[4 * 4096];

  const int tid = threadIdx.x;
  const int lane = tid & 63;
  const int wave = tid >> 6;
  const int g = lane >> 4;
  const int lr = lane & 15;
  const int bh = blockIdx.y;
  const int b = bh >> 4, h = bh & 15;
  const int q0 = blockIdx.x << 7;   // 128 q-rows per block

  short8 qhi[2][6], qlo[2][6];
  {
    const float scale = 0.07216878364870323f;  // 1/sqrt(192)
#pragma unroll
    for (int tl = 0; tl < 2; ++tl) {
      const int tok = b * N_ + q0 + wave * 32 + tl * 16 + lr;
      const float* qp = q_up + (size_t)tok * (H_ * QHD_) + h * QHD_;
#pragma unroll
      for (int c = 0; c < 6; ++c) {
        const float* src = qp + c * 32 + g * 8;
#pragma unroll
        for (int j = 0; j < 8; ++j) {
          short a, bq; bf_split(src[j] * scale, a, bq);
          qhi[tl][c][j] = a; qlo[tl][c][j] = bq;
        }
      }
    }
  }

  f32x4 acc_o[2][8];
#pragma unroll
  for (int tl = 0; tl < 2; ++tl)
#pragma unroll
    for (int i = 0; i < 8; ++i) acc_o[tl][i] = (f32x4){0.f, 0.f, 0.f, 0.f};
  float m_r[2][4], l_r[2][4];
#pragma unroll
  for (int tl = 0; tl < 2; ++tl)
#pragma unroll
    for (int j = 0; j < 4; ++j) { m_r[tl][j] = -1e30f; l_r[tl][j] = 0.f; }

  for (int kt = 0; kt < N_ / 32; ++kt) {
    __syncthreads();
    {
      const uint8_t* gkn = Kn + (((size_t)bh * 64 + kt) << 14);
      const uint8_t* gkp = Kp + (((size_t)b * 64 + kt) << 13);
      const uint8_t* gv  = Vv + (((size_t)bh * 64 + kt) << 14);
#pragma unroll
      for (int i = 0; i < 4; ++i)
        gload16(gkn + (wave * 4 + i) * 1024 + lane * 16, Ksn + (wave * 4 + i) * 1024);
#pragma unroll
      for (int i = 0; i < 2; ++i)
        gload16(gkp + (wave * 2 + i) * 1024 + lane * 16, Ksp + (wave * 2 + i) * 1024);
#pragma unroll
      for (int i = 0; i < 4; ++i)
        gload16(gv + (wave * 4 + i) * 1024 + lane * 16, Vs + (wave * 4 + i) * 1024);
    }
    __syncthreads();

    // ---- QK^T: per K-fragment read -> 6 MFMAs ----
    f32x4 accs[2][2];
#pragma unroll
    for (int t = 0; t < 2; ++t) {
      f32x4 aA = {0.f, 0.f, 0.f, 0.f};
      f32x4 aB = {0.f, 0.f, 0.f, 0.f};
      const int krow = t * 16 + lr;
      const int sw = (krow & 7) << 4;
      const uint8_t* kb = Ksn + krow * 512;
#pragma unroll
      for (int c = 0; c < 4; ++c) {
        short8 kh = *(const short8*)(kb + ((16 * (c * 4 + g)) ^ sw));
        short8 kl = *(const short8*)(kb + ((16 * (c * 4 + g + 16)) ^ sw));
        aA = __builtin_amdgcn_mfma_f32_16x16x32_bf16(qhi[0][c], kh, aA, 0, 0, 0);
        aA = __builtin_amdgcn_mfma_f32_16x16x32_bf16(qhi[0][c], kl, aA, 0, 0, 0);
        aA = __builtin_amdgcn_mfma_f32_16x16x32_bf16(qlo[0][c], kh, aA, 0, 0, 0);
        aB = __builtin_amdgcn_mfma_f32_16x16x32_bf16(qhi[1][c], kh, aB, 0, 0, 0);
        aB = __builtin_amdgcn_mfma_f32_16x16x32_bf16(qhi[1][c], kl, aB, 0, 0, 0);
        aB = __builtin_amdgcn_mfma_f32_16x16x32_bf16(qlo[1][c], kh, aB, 0, 0, 0);
      }
      const uint8_t* pb = Ksp + krow * 256;
#pragma unroll
      for (int c2 = 0; c2 < 2; ++c2) {
        short8 kh = *(const short8*)(pb + ((16 * (c2 * 4 + g)) ^ sw));
        short8 kl = *(const short8*)(pb + ((16 * (c2 * 4 + g + 8)) ^ sw));
        aA = __builtin_amdgcn_mfma_f32_16x16x32_bf16(qhi[0][4 + c2], kh, aA, 0, 0, 0);
        aA = __builtin_amdgcn_mfma_f32_16x16x32_bf16(qhi[0][4 + c2], kl, aA, 0, 0, 0);
        aA = __builtin_amdgcn_mfma_f32_16x16x32_bf16(qlo[0][4 + c2], kh, aA, 0, 0, 0);
        aB = __builtin_amdgcn_mfma_f32_16x16x32_bf16(qhi[1][4 + c2], kh, aB, 0, 0, 0);
        aB = __builtin_amdgcn_mfma_f32_16x16x32_bf16(qhi[1][4 + c2], kl, aB, 0, 0, 0);
        aB = __builtin_amdgcn_mfma_f32_16x16x32_bf16(qlo[1][4 + c2], kh, aB, 0, 0, 0);
      }
      accs[0][t] = aA; accs[1][t] = aB;
    }

    // ---- online softmax per tile (row = g*4+j lives in 16-lane group) ----
    float fac[2][4], p0[2][4], p1[2][4];
#pragma unroll
    for (int tl = 0; tl < 2; ++tl)
#pragma unroll
      for (int j = 0; j < 4; ++j) {
        float rm = fmaxf(accs[tl][0][j], accs[tl][1][j]);
        rm = fmaxf(rm, __shfl_xor(rm, 1, 64));
        rm = fmaxf(rm, __shfl_xor(rm, 2, 64));
        rm = fmaxf(rm, __shfl_xor(rm, 4, 64));
        rm = fmaxf(rm, __shfl_xor(rm, 8, 64));
        float mn = fmaxf(m_r[tl][j], rm);
        fac[tl][j] = __expf(m_r[tl][j] - mn);
        m_r[tl][j] = mn;
        p0[tl][j] = __expf(accs[tl][0][j] - mn);
        p1[tl][j] = __expf(accs[tl][1][j] - mn);
        float rs = p0[tl][j] + p1[tl][j];
        rs += __shfl_xor(rs, 1, 64);
        rs += __shfl_xor(rs, 2, 64);
        rs += __shfl_xor(rs, 4, 64);
        rs += __shfl_xor(rs, 8, 64);
        l_r[tl][j] = l_r[tl][j] * fac[tl][j] + rs;
      }
#pragma unroll
    for (int tl = 0; tl < 2; ++tl)
#pragma unroll
      for (int dt = 0; dt < 8; ++dt)
#pragma unroll
        for (int j = 0; j < 4; ++j) acc_o[tl][dt][j] *= fac[tl][j];

    // ---- P (hi/lo) -> per-wave swizzled LDS (transpose D->A layout) ----
#pragma unroll
    for (int tl = 0; tl < 2; ++tl) {
      uint8_t* pw = Ps + wave * 4096 + tl * 2048;
#pragma unroll
      for (int j = 0; j < 4; ++j) {
        int r = g * 4 + j;
        int rsw = (r & 7) << 4;
        uint8_t* rowp = pw + r * 128;
#pragma unroll
        for (int t = 0; t < 2; ++t) {
          float p = t ? p1[tl][j] : p0[tl][j];
          int k = t * 16 + lr;
          short a, bq; bf_split(p, a, bq);
          *(short*)(rowp + ((((k >> 3) + 0) * 16) ^ rsw) + (k & 7) * 2) = a;
          *(short*)(rowp + ((((k >> 3) + 4) * 16) ^ rsw) + (k & 7) * 2) = bq;
        }
      }
    }

    // ---- PV: per V-fragment read -> 6 MFMAs ----
    {
      const uint8_t* prA = Ps + wave * 4096 + lr * 128;
      const uint8_t* prB = prA + 2048;
      const int psw = (lr & 7) << 4;
      short8 phA = *(const short8*)(prA + ((16 * g) ^ psw));
      short8 plA = *(const short8*)(prA + ((16 * (4 + g)) ^ psw));
      short8 phB = *(const short8*)(prB + ((16 * g) ^ psw));
      short8 plB = *(const short8*)(prB + ((16 * (4 + g)) ^ psw));
#pragma unroll
      for (int dt = 0; dt < 8; ++dt) {
        int dcol = dt * 16 + lr;
        const uint8_t* vb = Vs + dcol * 128;
        int vsw = (dcol & 7) << 4;
        short8 vh = *(const short8*)(vb + ((16 * g) ^ vsw));
        short8 vl = *(const short8*)(vb + ((16 * (4 + g)) ^ vsw));
        acc_o[0][dt] = __builtin_amdgcn_mfma_f32_16x16x32_bf16(phA, vh, acc_o[0][dt], 0, 0, 0);
        acc_o[0][dt] = __builtin_amdgcn_mfma_f32_16x16x32_bf16(phA, vl, acc_o[0][dt], 0, 0, 0);
        acc_o[0][dt] = __builtin_amdgcn_mfma_f32_16x16x32_bf16(plA, vh, acc_o[0][dt], 0, 0, 0);
        acc_o[1][dt] = __builtin_amdgcn_mfma_f32_16x16x32_bf16(phB, vh, acc_o[1][dt], 0, 0, 0);
        acc_o[1][dt] = __builtin_amdgcn_mfma_f32_16x16x32_bf16(phB, vl, acc_o[1][dt], 0, 0, 0);
        acc_o[1][dt] = __builtin_amdgcn_mfma_f32_16x16x32_bf16(plB, vh, acc_o[1][dt], 0, 0, 0);
      }
    }
  }

  // ---- epilogue ----
#pragma unroll
  for (int tl = 0; tl < 2; ++tl) {
    float inv[4];
#pragma unroll
    for (int j = 0; j < 4; ++j) inv[j] = 1.f / l_r[tl][j];
    const int tokb = b * N_ + q0 + wave * 32 + tl * 16 + g * 4;
#pragma unroll
    for (int j = 0; j < 4; ++j) {
      float* orow = aout + (size_t)(tokb + j) * (H_ * DV_) + h * DV_;
#pragma unroll
      for (int dt = 0; dt < 8; ++dt)
        orow[dt * 16 + lr] = acc_o[tl][dt][j] * inv[j];
    }
  }
}

// ---------------------------------------------------------------------------
extern "C" void kernel_launch(void* const* d_in, const int* in_sizes, int n_in,
                              void* d_out, int out_size, void* d_ws, size_t ws_size,
                              hipStream_t stream) {
  (void)in_sizes; (void)n_in; (void)out_size; (void)ws_size;
  const float* x         = (const float*)d_in[0];
  const float* Wq_down   = (const float*)d_in[1];
  const float* q_norm_w  = (const float*)d_in[2];
  const float* Wq_up     = (const float*)d_in[3];
  const float* Wkv_down  = (const float*)d_in[4];
  const float* kv_norm_w = (const float*)d_in[5];
  const float* Wkv_up    = (const float*)d_in[6];
  const float* Wo        = (const float*)d_in[7];
  const int* pos_ids     = (const int*)d_in[9];
  float* out = (float*)d_out;

  // ws byte layout (peak ~167MB < 194MB proven):
  uint8_t* W = (uint8_t*)d_ws;
  uint8_t* Xi    = W;                          // 48MB x-image (also q-norm img 36MB)
  uint8_t* Bslot = W + 50331648;               // 28.3MB weight images
  float*   qtkv  = (float*)(W + 79691776);     // 4096 x 2176 fp32 (34MB)
  float*   q_up  = (float*)(W + 115343360);    // 4096 x 3072 fp32 (48MB)
  uint8_t* Kpimg = W + 165675008;              // 1MB
  uint8_t* KvAimg= W + 67108864;               // 12MB (kv rmsnorm image)
  uint8_t* WkvBimg=W + 79691776;               // 12MB (reuses dead qtkv)
  float*   kv_up = (float*)(W + 0);            // 64MB fp32 (reuses dead x/q images)
  uint8_t* Knimg = W + 67108864;               // 32MB
  float*   a_out = (float*)(W + 0);            // 32MB (reuses dead kv_up)
  uint8_t* A2img = W + 33554432;               // 48MB
  uint8_t* Woimg = W + 100663296;              // 24MB
  uint8_t* Vimg  = (uint8_t*)d_out;            // 32MB (dead before final GEMM)

  dim3 blk(256);
  // down-proj: x-img, [Wq_down | Wkv_down]-img, one GEMM (N = 1536+640pad)
  conv_a_kernel<<<4096, blk, 0, stream>>>(x, Xi, 2048, 96, 4096 * 256);
  conv_b_kernel<<<dim3(24, 32), blk, 0, stream>>>(Wq_down, Bslot, 2048, 1536, 0, 96);
  conv_b_kernel<<<dim3(10, 32), blk, 0, stream>>>(Wkv_down, Bslot, 2048, 576, 12, 96);
  gemm_bf16_kernel<<<dim3(17, 32), blk, 0, stream>>>(Xi, Bslot, qtkv, 2176, 96);
  // q path
  rmsnorm_img_kernel<<<4096, blk, 0, stream>>>(qtkv, q_norm_w, Xi, 1536, 2176, 72);
  conv_b_kernel<<<dim3(48, 24), blk, 0, stream>>>(Wq_up, Bslot, 1536, 3072, 0, 72);
  gemm_bf16_kernel<<<dim3(24, 32), blk, 0, stream>>>(Xi, Bslot, q_up, 3072, 72);
  rope_q_kernel<<<256, blk, 0, stream>>>(q_up, pos_ids);
  // kv path (consume qtkv, then reuse its space)
  rope_k_kernel<<<16, blk, 0, stream>>>(qtkv, pos_ids, Kpimg);
  rmsnorm_img_kernel<<<4096, blk, 0, stream>>>(qtkv + 1536, kv_norm_w, KvAimg, 512, 2176, 24);
  conv_b_kernel<<<dim3(64, 8), blk, 0, stream>>>(Wkv_up, WkvBimg, 512, 4096, 0, 24);
  gemm_bf16_kernel<<<dim3(32, 32), blk, 0, stream>>>(KvAimg, WkvBimg, kv_up, 4096, 24);
  conv_kn_kernel<<<dim3(64, 32), blk, 0, stream>>>(kv_up, Knimg);
  conv_v_kernel<<<dim3(64, 32), blk, 0, stream>>>(kv_up, Vimg);
  // attention (128 q-rows per block)
  attn_mfma_kernel<<<dim3(16, 32), blk, 0, stream>>>(q_up, Knimg, Kpimg, Vimg, a_out);
  // output projection
  conv_a_kernel<<<4096, blk, 0, stream>>>(a_out, A2img, 2048, 96, 4096 * 256);
  conv_b_kernel<<<dim3(32, 32), blk, 0, stream>>>(Wo, Woimg, 2048, 2048, 0, 96);
  gemm_bf16_kernel<<<dim3(16, 32), blk, 0, stream>>>(A2img, Woimg, out, 2048, 96);
}